// Round 7
// baseline (68836.755 us; speedup 1.0000x reference)
//
#include <hip/hip_runtime.h>

typedef __attribute__((ext_vector_type(8))) short short8;
typedef __attribute__((ext_vector_type(4))) float f32x4;

#define NBLK 512
#define NTHR 512
#define BSZ 128
#define HID 1024
#define INP 256
#define LAT 512
#define OUTD 256

// ---- bf16 element offsets in ws ----
#define O_WIH0 0u
#define O_WHH0 1048576u
#define O_WIH1 5242880u
#define O_WHH1 9437184u
#define O_WFC1 13631488u
#define O_WFC2 14680064u
#define O_WGH  14942208u      /* left half, [1024][1024] */
#define O_WGC  15990784u      /* left half, [1024][1024] */
#define O_ZB   17039360u
#define O_XB   17104896u
#define O_HZ   17137664u
#define O_CZB  17268736u
#define O_H0N  17399808u
#define O_H1N  17530880u
#define O_H0F  17661952u
#define O_H1F  17793024u
#define O_C0NB 17924096u
#define O_C1NB 18055168u
#define O_RB   18186240u
#define BF_END 18317312u
#define F32BASE (2u*BF_END)
#define OF_GHZ 0u
#define OF_GCZ 131072u
#define OF_CZ  262144u
#define OF_C0N 393216u
#define OF_C1N 524288u
#define OF_C0F 655360u
#define OF_C1F 786432u
#define F32CNT 917504u
#define BARBYTE (F32BASE + 4u*F32CNT)

#define LSTR 1032   /* LDS A stride in elements */

__device__ __forceinline__ unsigned short f2bf(float x) {
  union { float f; unsigned u; } v; v.f = x;
  return (unsigned short)((v.u + 0x7fffu + ((v.u >> 16) & 1u)) >> 16);
}
__device__ __forceinline__ float bf2f(unsigned short h) {
  union { unsigned u; float f; } v; v.u = ((unsigned)h) << 16;
  return v.f;
}
__device__ __forceinline__ float sigm(float x) { return 1.f / (1.f + __expf(-x)); }
__device__ __forceinline__ float ftanh(float x) { return 1.f - 2.f / (__expf(2.f * x) + 1.f); }
__device__ __forceinline__ unsigned packbf(float a, float b) {
  return (unsigned)f2bf(a) | ((unsigned)f2bf(b) << 16);
}

// coherent (agent-scope) accessors for cross-block activations
__device__ __forceinline__ unsigned long long ald64(const void* p) {
  return __hip_atomic_load((const unsigned long long*)p, __ATOMIC_RELAXED, __HIP_MEMORY_SCOPE_AGENT);
}
__device__ __forceinline__ unsigned ald32(const void* p) {
  return __hip_atomic_load((const unsigned*)p, __ATOMIC_RELAXED, __HIP_MEMORY_SCOPE_AGENT);
}
__device__ __forceinline__ float aldf(const float* p) {
  return __hip_atomic_load(p, __ATOMIC_RELAXED, __HIP_MEMORY_SCOPE_AGENT);
}
__device__ __forceinline__ void ast32(void* p, unsigned v) {
  __hip_atomic_store((unsigned*)p, v, __ATOMIC_RELAXED, __HIP_MEMORY_SCOPE_AGENT);
}
__device__ __forceinline__ void ast64(void* p, unsigned long long v) {
  __hip_atomic_store((unsigned long long*)p, v, __ATOMIC_RELAXED, __HIP_MEMORY_SCOPE_AGENT);
}
__device__ __forceinline__ void astf(float* p, float v) {
  __hip_atomic_store(p, v, __ATOMIC_RELAXED, __HIP_MEMORY_SCOPE_AGENT);
}

__device__ __forceinline__ short8 ldwf(const float* s) {
  const float4* p = (const float4*)s;
  float4 x = p[0], y = p[1];
  short8 r;
  r[0]=(short)f2bf(x.x); r[1]=(short)f2bf(x.y); r[2]=(short)f2bf(x.z); r[3]=(short)f2bf(x.w);
  r[4]=(short)f2bf(y.x); r[5]=(short)f2bf(y.y); r[6]=(short)f2bf(y.z); r[7]=(short)f2bf(y.w);
  return r;
}

__device__ __forceinline__ void conv4(const float* __restrict__ s, unsigned short* __restrict__ d,
                                      int n4, int gtid, int gsz) {
  const float4* s4 = (const float4*)s;
  ushort4* d4 = (ushort4*)d;
  for (int i = gtid; i < n4; i += gsz) {
    float4 v = s4[i];
    ushort4 o; o.x=f2bf(v.x); o.y=f2bf(v.y); o.z=f2bf(v.z); o.w=f2bf(v.w);
    d4[i] = o;
  }
}
__device__ __forceinline__ void convHalf(const float* __restrict__ s, unsigned short* __restrict__ d,
                                         int gtid, int gsz) {
  for (int i = gtid; i < (1024*1024)/4; i += gsz) {
    int row = i >> 8, c4 = (i & 255) * 4;
    float4 v = *(const float4*)(s + (size_t)row*2048 + c4);
    ushort4 o; o.x=f2bf(v.x); o.y=f2bf(v.y); o.z=f2bf(v.z); o.w=f2bf(v.w);
    *(ushort4*)(d + (size_t)row*1024 + c4) = o;
  }
}

// ---- tree-release grid barrier ----
// 16 groups x 32 blocks. Arrive: group RMW -> root RMW. Release: root epoch ->
// per-group scout (last arriver) -> group epoch. Max pollers per line: 31.
__device__ __forceinline__ void gbar(unsigned* bar, unsigned target, bool fence) {
  __syncthreads();
  if (threadIdx.x == 0) {
    const int g = (int)blockIdx.x >> 5;
    unsigned* cnt  = bar + g * 64;            // 256B spacing
    unsigned* gep  = bar + (16 + g) * 64;
    unsigned* root = bar + 32 * 64;
    unsigned* rep  = bar + 33 * 64;
    unsigned prev = __hip_atomic_fetch_add(cnt, 1u, __ATOMIC_RELEASE, __HIP_MEMORY_SCOPE_AGENT);
    if (prev == 31u) {
      __hip_atomic_store(cnt, 0u, __ATOMIC_RELAXED, __HIP_MEMORY_SCOPE_AGENT);
      unsigned p2 = __hip_atomic_fetch_add(root, 1u, __ATOMIC_RELEASE, __HIP_MEMORY_SCOPE_AGENT);
      if (p2 == 15u) {
        __hip_atomic_store(root, 0u, __ATOMIC_RELAXED, __HIP_MEMORY_SCOPE_AGENT);
        __hip_atomic_store(rep, target, __ATOMIC_RELEASE, __HIP_MEMORY_SCOPE_AGENT);
      } else {
        unsigned e = __hip_atomic_load(rep, __ATOMIC_RELAXED, __HIP_MEMORY_SCOPE_AGENT);
        int guard = 0;
        while (e < target) {
          __builtin_amdgcn_s_sleep(1);
          e = __hip_atomic_load(rep, __ATOMIC_RELAXED, __HIP_MEMORY_SCOPE_AGENT);
          if (++guard > (1 << 20)) break;
        }
      }
      __hip_atomic_store(gep, target, __ATOMIC_RELEASE, __HIP_MEMORY_SCOPE_AGENT);
    } else {
      unsigned e = __hip_atomic_load(gep, __ATOMIC_RELAXED, __HIP_MEMORY_SCOPE_AGENT);
      int guard = 0;
      while (e < target) {
        __builtin_amdgcn_s_sleep(1);
        e = __hip_atomic_load(gep, __ATOMIC_RELAXED, __HIP_MEMORY_SCOPE_AGENT);
        if (++guard > (1 << 20)) break;
      }
    }
    if (fence) __builtin_amdgcn_fence(__ATOMIC_ACQUIRE, "agent");
  }
  __syncthreads();
}

// cooperative stage of 16-row A slab into LDS via coherent 8B loads
template<int NQ0, int NQ1>
__device__ __forceinline__ void stage2(const unsigned short* s0, int st0,
                                       const unsigned short* s1, int st1,
                                       unsigned short* As, int R0, int tid) {
  constexpr int NQ = NQ0 + NQ1;
  for (int i = tid; i < 16 * NQ; i += NTHR) {
    int row = i / NQ, q = i - row * NQ;
    const unsigned short* s = (q < NQ0) ? s0 + (size_t)(R0 + row) * st0 + 4 * q
                                        : s1 + (size_t)(R0 + row) * st1 + 4 * (q - NQ0);
    *(unsigned long long*)(As + row * LSTR + 4 * q) = ald64(s);
  }
}

template<int NI>
__device__ __forceinline__ f32x4 mmK(const unsigned short* a, const unsigned short* w, f32x4 acc) {
#pragma unroll
  for (int i = 0; i < NI; ++i) {
    short8 af = *(const short8*)(a + 32 * i);
    short8 bf = *(const short8*)(w + 32 * i);
    acc = __builtin_amdgcn_mfma_f32_16x16x32_bf16(af, bf, acc, 0, 0, 0);
  }
  return acc;
}
template<int NI>
__device__ __forceinline__ f32x4 mmKf(const unsigned short* a, const float* w, f32x4 acc) {
#pragma unroll
  for (int i = 0; i < NI; ++i) {
    short8 af = *(const short8*)(a + 32 * i);
    short8 bf = ldwf(w + 32 * i);
    acc = __builtin_amdgcn_mfma_f32_16x16x32_bf16(af, bf, acc, 0, 0, 0);
  }
  return acc;
}

__device__ __forceinline__ void dumpw(float* gat, f32x4 acc, int kh, int cg, int lane) {
  int lm = lane & 15, lq = lane >> 4;
#pragma unroll
  for (int j = 0; j < 4; ++j)
    gat[(kh * 16 + lq * 4 + j) * 64 + 16 * cg + lm] = acc[j];
}
__device__ __forceinline__ float gs(const float* gat, int row, int col) {
  return gat[row * 64 + col] + gat[1024 + row * 64 + col];
}

__global__ __launch_bounds__(NTHR, 4)
void dec_kernel(const float* __restrict__ z, const int* __restrict__ seqp,
                const float* __restrict__ stok,
                const float* __restrict__ W_ih0, const float* __restrict__ W_hh0,
                const float* __restrict__ b_ih0, const float* __restrict__ b_hh0,
                const float* __restrict__ W_ih1, const float* __restrict__ W_hh1,
                const float* __restrict__ b_ih1, const float* __restrict__ b_hh1,
                const float* __restrict__ W_lh, const float* __restrict__ b_lh,
                const float* __restrict__ W_lc, const float* __restrict__ b_lc,
                const float* __restrict__ W_fc1, const float* __restrict__ b_fc1,
                const float* __restrict__ W_fc2, const float* __restrict__ b_fc2,
                const float* __restrict__ Wg_h, const float* __restrict__ bg_h,
                const float* __restrict__ Wg_c, const float* __restrict__ bg_c,
                float* __restrict__ out, unsigned char* __restrict__ ws) {
  __shared__ char smem[57344];
  unsigned short* As = (unsigned short*)smem;        // [16][1032] bf16
  float* gat = (float*)(smem + 33024);               // [2][16][64] f32

  unsigned short* bfb = (unsigned short*)ws;
  float* f32b = (float*)(ws + F32BASE);
  unsigned* bar = (unsigned*)(ws + BARBYTE);

  unsigned short* Zb  = bfb + O_ZB;
  unsigned short* Xb  = bfb + O_XB;
  unsigned short* Hz  = bfb + O_HZ;
  unsigned short* Czb = bfb + O_CZB;
  unsigned short* H0n = bfb + O_H0N;
  unsigned short* H1n = bfb + O_H1N;
  unsigned short* H0f = bfb + O_H0F;
  unsigned short* H1f = bfb + O_H1F;
  unsigned short* C0nb = bfb + O_C0NB;
  unsigned short* C1nb = bfb + O_C1NB;
  unsigned short* Rb  = bfb + O_RB;
  float* Ghz = f32b + OF_GHZ;
  float* Gcz = f32b + OF_GCZ;
  float* Cz  = f32b + OF_CZ;
  float* C0n = f32b + OF_C0N;
  float* C1n = f32b + OF_C1N;
  float* C0f = f32b + OF_C0F;
  float* C1f = f32b + OF_C1F;

  const int b = (int)blockIdx.x, tid = (int)threadIdx.x;
  const int lane = tid & 63, wave = tid >> 6;
  const int lm = lane & 15, lq8 = (lane >> 4) * 8;
  const int cg = wave & 3, kh = wave >> 2;
  const int gtid = b * NTHR + tid, gsz = NBLK * NTHR;

  const int k8 = b & 7, mm_ = (b >> 3) & 7, rt = b >> 6;
  const int ct = 8 * mm_ + k8;
  const int R0 = rt * 16;
  const int U0 = ct * 16;
  unsigned bt = 0;

  // ---- Ph_a: stage weights to bf16, init z/x ----
  conv4(z,     Zb,           (BSZ*LAT)/4, gtid, gsz);
  conv4(W_ih0, bfb + O_WIH0, 1048576/4, gtid, gsz);
  conv4(W_hh0, bfb + O_WHH0, 4194304/4, gtid, gsz);
  conv4(W_ih1, bfb + O_WIH1, 4194304/4, gtid, gsz);
  conv4(W_hh1, bfb + O_WHH1, 4194304/4, gtid, gsz);
  conv4(W_fc1, bfb + O_WFC1, 1048576/4, gtid, gsz);
  conv4(W_fc2, bfb + O_WFC2, 262144/4, gtid, gsz);
  convHalf(Wg_h, bfb + O_WGH, gtid, gsz);
  convHalf(Wg_c, bfb + O_WGC, gtid, gsz);
  for (int i = gtid; i < BSZ * INP; i += gsz) Xb[i] = f2bf(stok[i & (INP - 1)]);
  gbar(bar, ++bt, true);

  // ---- Ph_b: h_z / c_z ----
  if (ct < 32) {
    stage2<128,0>(Zb, LAT, Zb, LAT, As, R0, tid);
    __syncthreads();
    f32x4 acc = {};
    const float* Wf = (ct < 16) ? W_lh : W_lc;
    int jb = 64 * (ct & 15) + 16 * cg + lm;
    acc = mmKf<8>(As + lm*LSTR + kh*256 + lq8, Wf + (size_t)jb*LAT + kh*256 + lq8, acc);
    dumpw(gat, acc, kh, cg, lane);
    __syncthreads();
    int prow = tid >> 5, cp2 = 2 * (tid & 31);
    int j0 = 64 * (ct & 15) + cp2;
    const float* bl = (ct < 16) ? b_lh : b_lc;
    float v0 = ftanh(gs(gat, prow, cp2) + bl[j0]);
    float v1 = ftanh(gs(gat, prow, cp2 + 1) + bl[j0 + 1]);
    size_t gi0 = (size_t)(R0 + prow) * HID + j0;
    unsigned pk = packbf(v0, v1);
    if (ct < 16) {
      ast32(Hz + gi0, pk); ast32(H0f + gi0, pk); ast32(H1f + gi0, pk);
    } else {
      ast32(Czb + gi0, pk);
      float2 vv; vv.x = v0; vv.y = v1;
      unsigned long long uv = __builtin_bit_cast(unsigned long long, vv);
      ast64(Cz + gi0, uv); ast64(C0f + gi0, uv); ast64(C1f + gi0, uv);
    }
  }
  gbar(bar, ++bt, false);

  // ---- Ph_c: Ghz / Gcz ----
  if (ct < 32) {
    const unsigned short* Asrc = (ct < 16) ? Hz : Czb;
    stage2<256,0>(Asrc, HID, Asrc, HID, As, R0, tid);
    __syncthreads();
    f32x4 acc = {};
    const float* Wf = (ct < 16) ? Wg_h : Wg_c;
    int jb = 64 * (ct & 15) + 16 * cg + lm;
    acc = mmKf<16>(As + lm*LSTR + kh*512 + lq8, Wf + (size_t)jb*(2*HID) + HID + kh*512 + lq8, acc);
    dumpw(gat, acc, kh, cg, lane);
    __syncthreads();
    int prow = tid >> 5, cp2 = 2 * (tid & 31);
    int j0 = 64 * (ct & 15) + cp2;
    const float* bg = (ct < 16) ? bg_h : bg_c;
    float* G = (ct < 16) ? Ghz : Gcz;
    float2 vv; vv.x = gs(gat, prow, cp2) + bg[j0]; vv.y = gs(gat, prow, cp2 + 1) + bg[j0 + 1];
    ast64(G + (size_t)(R0 + prow) * HID + j0, __builtin_bit_cast(unsigned long long, vv));
  }
  gbar(bar, ++bt, true);

  // ---- step-invariant preloads ----
  const int upre = U0 + (tid & 15);
  const float bi0 = b_ih0[upre] + b_hh0[upre];
  const float bf0 = b_ih0[HID+upre] + b_hh0[HID+upre];
  const float bg0 = b_ih0[2*HID+upre] + b_hh0[2*HID+upre];
  const float bo0 = b_ih0[3*HID+upre] + b_hh0[3*HID+upre];
  const float bi1 = b_ih1[upre] + b_hh1[upre];
  const float bf1 = b_ih1[HID+upre] + b_hh1[HID+upre];
  const float bg1 = b_ih1[2*HID+upre] + b_hh1[2*HID+upre];
  const float bo1 = b_ih1[3*HID+upre] + b_hh1[3*HID+upre];

  const int prow = tid >> 5, cp2 = 2 * (tid & 31);
  const int c03 = 64 * (ct & 15);
  const int role3 = (ct < 16) ? 0 : (ct < 32) ? 1 : (ct < 48) ? 2 : 3;
  float pb0 = 0.f, pb1 = 0.f, pg0 = 0.f, pg1 = 0.f, pz0 = 0.f, pz1 = 0.f;
  if (role3 == 0) { pb0 = b_fc1[c03 + cp2]; pb1 = b_fc1[c03 + cp2 + 1]; }
  else if (role3 == 1) {
    size_t gi = (size_t)(R0 + prow) * HID + c03 + cp2;
    pg0 = Ghz[gi]; pg1 = Ghz[gi + 1]; pz0 = bf2f(Hz[gi]); pz1 = bf2f(Hz[gi + 1]);
  } else if (role3 == 2) {
    size_t gi = (size_t)(R0 + prow) * HID + c03 + cp2;
    pg0 = Gcz[gi]; pg1 = Gcz[gi + 1]; pz0 = Cz[gi]; pz1 = Cz[gi + 1];
  }
  const int c04 = 64 * (ct - 48);
  if (ct >= 48 && ct < 52) { pb0 = b_fc2[c04 + cp2]; pb1 = b_fc2[c04 + cp2 + 1]; }

  const int wrow = (lm >> 2) * HID + U0 + 4 * cg + (lm & 3);
  const unsigned short* arow0 = As + lm * LSTR + lq8;
  const int T = seqp[0];

  for (int st = 0; st < T; ++st) {
    // ---- P1 ----
    {
      stage2<64,192>(Xb, INP, H0f, HID, As, R0, tid);
      __syncthreads();
      f32x4 acc = {};
      if (kh == 0) {
        acc = mmK<8>(arow0, bfb + O_WIH0 + (size_t)wrow*INP + lq8, acc);
        acc = mmK<8>(arow0 + 256, bfb + O_WHH0 + (size_t)wrow*HID + lq8, acc);
      } else {
        acc = mmK<16>(arow0 + 512, bfb + O_WHH0 + (size_t)wrow*HID + 256 + lq8, acc);
      }
      __syncthreads();
      stage2<64,0>(H0f + 768, HID, H0f, HID, As, R0, tid);
      __syncthreads();
      if (kh == 0) acc = mmK<4>(arow0, bfb + O_WHH0 + (size_t)wrow*HID + 768 + lq8, acc);
      else         acc = mmK<4>(arow0 + 128, bfb + O_WHH0 + (size_t)wrow*HID + 896 + lq8, acc);
      dumpw(gat, acc, kh, cg, lane);
      __syncthreads();
      if (tid < 256) {
        int pr = tid >> 4, pu = tid & 15, pc = pu >> 2, pd = pu & 3;
        float si = gs(gat, pr, 16*pc + pd),     sf = gs(gat, pr, 16*pc + 4 + pd);
        float sg = gs(gat, pr, 16*pc + 8 + pd), so = gs(gat, pr, 16*pc + 12 + pd);
        float gi_ = sigm(si + bi0), gf_ = sigm(sf + bf0);
        float gg_ = ftanh(sg + bg0), go_ = sigm(so + bo0);
        size_t gix = (size_t)(R0 + pr) * HID + U0 + pu;
        float cn = gf_ * aldf(C0f + gix) + gi_ * gg_;
        unsigned short hb = f2bf(go_ * ftanh(cn)), cb = f2bf(cn);
        unsigned ho = (unsigned)__shfl_xor((int)(unsigned)hb, 1);
        unsigned co = (unsigned)__shfl_xor((int)(unsigned)cb, 1);
        if ((tid & 1) == 0) {
          ast32(H0n + gix, (unsigned)hb | ((ho & 0xffffu) << 16));
          ast32(C0nb + gix, (unsigned)cb | ((co & 0xffffu) << 16));
        }
        astf(C0n + gix, cn);
      }
      gbar(bar, ++bt, false);
    }
    // ---- P2 ----
    {
      stage2<256,0>(H0n, HID, H0n, HID, As, R0, tid);
      __syncthreads();
      f32x4 acc = {};
      acc = mmK<16>(arow0 + kh*512, bfb + O_WIH1 + (size_t)wrow*HID + kh*512 + lq8, acc);
      __syncthreads();
      stage2<256,0>(H1f, HID, H1f, HID, As, R0, tid);
      __syncthreads();
      acc = mmK<16>(arow0 + kh*512, bfb + O_WHH1 + (size_t)wrow*HID + kh*512 + lq8, acc);
      dumpw(gat, acc, kh, cg, lane);
      __syncthreads();
      if (tid < 256) {
        int pr = tid >> 4, pu = tid & 15, pc = pu >> 2, pd = pu & 3;
        float si = gs(gat, pr, 16*pc + pd),     sf = gs(gat, pr, 16*pc + 4 + pd);
        float sg = gs(gat, pr, 16*pc + 8 + pd), so = gs(gat, pr, 16*pc + 12 + pd);
        float gi_ = sigm(si + bi1), gf_ = sigm(sf + bf1);
        float gg_ = ftanh(sg + bg1), go_ = sigm(so + bo1);
        size_t gix = (size_t)(R0 + pr) * HID + U0 + pu;
        float cn = gf_ * aldf(C1f + gix) + gi_ * gg_;
        unsigned short hb = f2bf(go_ * ftanh(cn)), cb = f2bf(cn);
        unsigned ho = (unsigned)__shfl_xor((int)(unsigned)hb, 1);
        unsigned co = (unsigned)__shfl_xor((int)(unsigned)cb, 1);
        if ((tid & 1) == 0) {
          ast32(H1n + gix, (unsigned)hb | ((ho & 0xffffu) << 16));
          ast32(C1nb + gix, (unsigned)cb | ((co & 0xffffu) << 16));
        }
        astf(C1n + gix, cn);
      }
      gbar(bar, ++bt, false);
    }
    // ---- P3 ----
    {
      if (role3 < 3) {
        const unsigned short* A3 = (role3 == 0) ? H1n : (role3 == 1) ? H0n : C0nb;
        const unsigned short* W3 = bfb + ((role3 == 0) ? O_WFC1 : (role3 == 1) ? O_WGH : O_WGC);
        stage2<256,0>(A3, HID, A3, HID, As, R0, tid);
        __syncthreads();
        int j3 = c03 + 16 * cg + lm;
        f32x4 acc = {};
        acc = mmK<16>(arow0 + kh*512, W3 + (size_t)j3*HID + kh*512 + lq8, acc);
        dumpw(gat, acc, kh, cg, lane);
        __syncthreads();
        float s0 = gs(gat, prow, cp2), s1 = gs(gat, prow, cp2 + 1);
        size_t gi0 = (size_t)(R0 + prow) * HID + c03 + cp2;
        if (role3 == 0) {
          float v0 = s0 + pb0, v1 = s1 + pb1;
          ast32(Rb + gi0, packbf(v0 > 0.f ? v0 : 0.f, v1 > 0.f ? v1 : 0.f));
        } else if (role3 == 1) {
          unsigned hp = ald32(H0n + gi0);
          float g0 = sigm(s0 + pg0), g1 = sigm(s1 + pg1);
          float n0 = g0 * bf2f((unsigned short)(hp & 0xffffu)) + (1.f - g0) * pz0;
          float n1 = g1 * bf2f((unsigned short)(hp >> 16)) + (1.f - g1) * pz1;
          ast32(H0f + gi0, packbf(n0, n1));
        } else {
          float2 cc = __builtin_bit_cast(float2, ald64(C0n + gi0));
          float g0 = sigm(s0 + pg0), g1 = sigm(s1 + pg1);
          float2 r; r.x = g0 * cc.x + (1.f - g0) * pz0; r.y = g1 * cc.y + (1.f - g1) * pz1;
          ast64(C0f + gi0, __builtin_bit_cast(unsigned long long, r));
        }
      }
      gbar(bar, ++bt, false);
    }
    // ---- P4 ----
    {
      bool isfc2 = (ct >= 48 && ct < 52);
      if (isfc2 || role3 == 1 || role3 == 2) {
        const unsigned short* A4 = isfc2 ? Rb : (role3 == 1) ? H1n : C1nb;
        const unsigned short* W4 = bfb + (isfc2 ? O_WFC2 : (role3 == 1) ? O_WGH : O_WGC);
        stage2<256,0>(A4, HID, A4, HID, As, R0, tid);
        __syncthreads();
        int j4 = (isfc2 ? c04 : c03) + 16 * cg + lm;
        f32x4 acc = {};
        acc = mmK<16>(arow0 + kh*512, W4 + (size_t)j4*HID + kh*512 + lq8, acc);
        dumpw(gat, acc, kh, cg, lane);
        __syncthreads();
        float s0 = gs(gat, prow, cp2), s1 = gs(gat, prow, cp2 + 1);
        if (isfc2) {
          float v0 = s0 + pb0, v1 = s1 + pb1;
          size_t oix = ((size_t)(R0 + prow) * T + st) * OUTD + c04 + cp2;
          float2 vv; vv.x = v0; vv.y = v1;
          *(float2*)(out + oix) = vv;
          ast32(Xb + (size_t)(R0 + prow) * INP + c04 + cp2, packbf(v0, v1));
        } else if (role3 == 1) {
          size_t gi0 = (size_t)(R0 + prow) * HID + c03 + cp2;
          unsigned hp = ald32(H1n + gi0);
          float g0 = sigm(s0 + pg0), g1 = sigm(s1 + pg1);
          float n0 = g0 * bf2f((unsigned short)(hp & 0xffffu)) + (1.f - g0) * pz0;
          float n1 = g1 * bf2f((unsigned short)(hp >> 16)) + (1.f - g1) * pz1;
          ast32(H1f + gi0, packbf(n0, n1));
        } else {
          size_t gi0 = (size_t)(R0 + prow) * HID + c03 + cp2;
          float2 cc = __builtin_bit_cast(float2, ald64(C1n + gi0));
          float g0 = sigm(s0 + pg0), g1 = sigm(s1 + pg1);
          float2 r; r.x = g0 * cc.x + (1.f - g0) * pz0; r.y = g1 * cc.y + (1.f - g1) * pz1;
          ast64(C1f + gi0, __builtin_bit_cast(unsigned long long, r));
        }
      }
      gbar(bar, ++bt, false);
    }
  }
}

extern "C" void kernel_launch(void* const* d_in, const int* in_sizes, int n_in,
                              void* d_out, int out_size, void* d_ws, size_t ws_size,
                              hipStream_t stream) {
  unsigned char* ws = (unsigned char*)d_ws;
  hipMemsetAsync(ws + BARBYTE, 0, 16384, stream);

  dec_kernel<<<dim3(NBLK), dim3(NTHR), 0, stream>>>(
      (const float*)d_in[0], (const int*)d_in[1], (const float*)d_in[2],
      (const float*)d_in[3], (const float*)d_in[4], (const float*)d_in[5], (const float*)d_in[6],
      (const float*)d_in[7], (const float*)d_in[8], (const float*)d_in[9], (const float*)d_in[10],
      (const float*)d_in[11], (const float*)d_in[12], (const float*)d_in[13], (const float*)d_in[14],
      (const float*)d_in[15], (const float*)d_in[16], (const float*)d_in[17], (const float*)d_in[18],
      (const float*)d_in[19], (const float*)d_in[20], (const float*)d_in[21], (const float*)d_in[22],
      (float*)d_out, ws);
}

// Round 8
// 43132.269 us; speedup vs baseline: 1.5959x; 1.5959x over previous
//
#include <hip/hip_runtime.h>

typedef __attribute__((ext_vector_type(8))) short short8;
typedef __attribute__((ext_vector_type(4))) float f32x4;

#define NTHR 512
#define BSZ 128
#define HID 1024
#define INP 256
#define LAT 512
#define OUTD 256

// ---- bf16 element offsets in ws ----
#define O_WIH0 0u
#define O_WHH0 1048576u
#define O_WIH1 5242880u
#define O_WHH1 9437184u
#define O_WFC1 13631488u
#define O_WFC2 14680064u
#define O_WGH  14942208u      /* left half, [1024][1024] */
#define O_WGC  15990784u      /* left half, [1024][1024] */
#define O_ZB   17039360u
#define O_XB   17104896u
#define O_HZ   17137664u
#define O_CZB  17268736u
#define O_H0N  17399808u
#define O_H1N  17530880u
#define O_H0F  17661952u
#define O_H1F  17793024u
#define O_C0NB 17924096u
#define O_C1NB 18055168u
#define O_RB   18186240u
#define BF_END 18317312u
#define F32BASE (2u*BF_END)
#define OF_GHZ 0u
#define OF_GCZ 131072u
#define OF_CZ  262144u
#define OF_C0N 393216u
#define OF_C1N 524288u
#define OF_C0F 655360u
#define OF_C1F 786432u

__device__ __forceinline__ unsigned short f2bf(float x) {
  union { float f; unsigned u; } v; v.f = x;
  return (unsigned short)((v.u + 0x7fffu + ((v.u >> 16) & 1u)) >> 16);
}
__device__ __forceinline__ float bf2f(unsigned short h) {
  union { unsigned u; float f; } v; v.u = ((unsigned)h) << 16;
  return v.f;
}
__device__ __forceinline__ float sigm(float x) { return 1.f / (1.f + __expf(-x)); }
__device__ __forceinline__ float ftanh(float x) { return 1.f - 2.f / (__expf(2.f * x) + 1.f); }
__device__ __forceinline__ unsigned packbf(float a, float b) {
  return (unsigned)f2bf(a) | ((unsigned)f2bf(b) << 16);
}
__device__ __forceinline__ short8 ldwf(const float* s) {
  const float4* p = (const float4*)s;
  float4 x = p[0], y = p[1];
  short8 r;
  r[0]=(short)f2bf(x.x); r[1]=(short)f2bf(x.y); r[2]=(short)f2bf(x.z); r[3]=(short)f2bf(x.w);
  r[4]=(short)f2bf(y.x); r[5]=(short)f2bf(y.y); r[6]=(short)f2bf(y.z); r[7]=(short)f2bf(y.w);
  return r;
}

__device__ __forceinline__ void conv4(const float* __restrict__ s, unsigned short* __restrict__ d,
                                      int n4, int gtid, int gsz) {
  const float4* s4 = (const float4*)s;
  ushort4* d4 = (ushort4*)d;
  for (int i = gtid; i < n4; i += gsz) {
    float4 v = s4[i];
    ushort4 o; o.x=f2bf(v.x); o.y=f2bf(v.y); o.z=f2bf(v.z); o.w=f2bf(v.w);
    d4[i] = o;
  }
}
__device__ __forceinline__ void convHalf(const float* __restrict__ s, unsigned short* __restrict__ d,
                                         int gtid, int gsz) {
  for (int i = gtid; i < (1024*1024)/4; i += gsz) {
    int row = i >> 8, c4 = (i & 255) * 4;
    float4 v = *(const float4*)(s + (size_t)row*2048 + c4);
    ushort4 o; o.x=f2bf(v.x); o.y=f2bf(v.y); o.z=f2bf(v.z); o.w=f2bf(v.w);
    *(ushort4*)(d + (size_t)row*1024 + c4) = o;
  }
}

template<int NI>
__device__ __forceinline__ f32x4 mmK(const unsigned short* a, const unsigned short* w, f32x4 acc) {
#pragma unroll
  for (int i = 0; i < NI; ++i) {
    short8 af = *(const short8*)(a + 32 * i);
    short8 bf = *(const short8*)(w + 32 * i);
    acc = __builtin_amdgcn_mfma_f32_16x16x32_bf16(af, bf, acc, 0, 0, 0);
  }
  return acc;
}
template<int NI>
__device__ __forceinline__ f32x4 mmKf(const unsigned short* a, const float* w, f32x4 acc) {
#pragma unroll
  for (int i = 0; i < NI; ++i) {
    short8 af = *(const short8*)(a + 32 * i);
    short8 bf = ldwf(w + 32 * i);
    acc = __builtin_amdgcn_mfma_f32_16x16x32_bf16(af, bf, acc, 0, 0, 0);
  }
  return acc;
}

__device__ __forceinline__ void dumpw(float* gat, f32x4 acc, int kh, int cg, int lane) {
  int lm = lane & 15, lq = lane >> 4;
#pragma unroll
  for (int j = 0; j < 4; ++j)
    gat[(kh * 16 + lq * 4 + j) * 64 + 16 * cg + lm] = acc[j];
}
__device__ __forceinline__ float gs(const float* gat, int row, int col) {
  return gat[row * 64 + col] + gat[1024 + row * 64 + col];
}

// block decode shared by phase kernels
#define DEC \
  const int b=(int)blockIdx.x, tid=(int)threadIdx.x; \
  const int lane=tid&63, wave=tid>>6; \
  const int lm=lane&15, lq8=(lane>>4)*8; \
  const int cg=wave&3, kh=wave>>2; \
  const int ct=8*((b>>3)&7)+(b&7); \
  const int R0=(b>>6)*16, U0=ct*16; \
  unsigned short* bfb=(unsigned short*)ws; \
  float* f32b=(float*)(ws+F32BASE); \
  (void)U0; (void)f32b; (void)lq8; (void)kh; (void)cg; (void)lm; (void)lane; (void)wave;

// ---- prologue: stage weights + z to bf16, init x ----
__global__ __launch_bounds__(256)
void k_conv(const float* __restrict__ z, const float* __restrict__ stok,
            const float* __restrict__ W_ih0, const float* __restrict__ W_hh0,
            const float* __restrict__ W_ih1, const float* __restrict__ W_hh1,
            const float* __restrict__ W_fc1, const float* __restrict__ W_fc2,
            const float* __restrict__ Wg_h, const float* __restrict__ Wg_c,
            unsigned char* __restrict__ ws) {
  int gtid = (int)blockIdx.x * 256 + (int)threadIdx.x, gsz = (int)gridDim.x * 256;
  unsigned short* bfb = (unsigned short*)ws;
  conv4(z,     bfb + O_ZB,   (BSZ*LAT)/4, gtid, gsz);
  conv4(W_ih0, bfb + O_WIH0, 1048576/4, gtid, gsz);
  conv4(W_hh0, bfb + O_WHH0, 4194304/4, gtid, gsz);
  conv4(W_ih1, bfb + O_WIH1, 4194304/4, gtid, gsz);
  conv4(W_hh1, bfb + O_WHH1, 4194304/4, gtid, gsz);
  conv4(W_fc1, bfb + O_WFC1, 1048576/4, gtid, gsz);
  conv4(W_fc2, bfb + O_WFC2, 262144/4, gtid, gsz);
  convHalf(Wg_h, bfb + O_WGH, gtid, gsz);
  convHalf(Wg_c, bfb + O_WGC, gtid, gsz);
  for (int i = gtid; i < BSZ * INP; i += gsz) (bfb + O_XB)[i] = f2bf(stok[i & (INP - 1)]);
}

// ---- prologue: h_z / c_z ----
__global__ __launch_bounds__(NTHR)
void k_phb(const float* __restrict__ W_lh, const float* __restrict__ b_lh,
           const float* __restrict__ W_lc, const float* __restrict__ b_lc,
           unsigned char* __restrict__ ws) {
  __shared__ float gat[2048];
  DEC
  if (ct >= 32) return;
  const float* Wf = (ct < 16) ? W_lh : W_lc;
  int jb = 64 * (ct & 15) + 16 * cg + lm;
  f32x4 acc = {};
  acc = mmKf<8>(bfb + O_ZB + (size_t)(R0 + lm) * LAT + kh * 256 + lq8,
                Wf + (size_t)jb * LAT + kh * 256 + lq8, acc);
  dumpw(gat, acc, kh, cg, lane);
  __syncthreads();
  int prow = tid >> 5, cp2 = 2 * (tid & 31);
  int j0 = 64 * (ct & 15) + cp2;
  size_t gi0 = (size_t)(R0 + prow) * HID + j0;
  if (ct < 16) {
    float v0 = ftanh(gs(gat, prow, cp2) + b_lh[j0]);
    float v1 = ftanh(gs(gat, prow, cp2 + 1) + b_lh[j0 + 1]);
    unsigned pk = packbf(v0, v1);
    *(unsigned*)(bfb + O_HZ + gi0) = pk;
    *(unsigned*)(bfb + O_H0F + gi0) = pk;
    *(unsigned*)(bfb + O_H1F + gi0) = pk;
  } else {
    float v0 = ftanh(gs(gat, prow, cp2) + b_lc[j0]);
    float v1 = ftanh(gs(gat, prow, cp2 + 1) + b_lc[j0 + 1]);
    *(unsigned*)(bfb + O_CZB + gi0) = packbf(v0, v1);
    float2 vv; vv.x = v0; vv.y = v1;
    *(float2*)(f32b + OF_CZ + gi0) = vv;
    *(float2*)(f32b + OF_C0F + gi0) = vv;
    *(float2*)(f32b + OF_C1F + gi0) = vv;
  }
}

// ---- prologue: Ghz / Gcz (right-half gate matmul, step-invariant) ----
__global__ __launch_bounds__(NTHR)
void k_phc(const float* __restrict__ Wg_h, const float* __restrict__ bg_h,
           const float* __restrict__ Wg_c, const float* __restrict__ bg_c,
           unsigned char* __restrict__ ws) {
  __shared__ float gat[2048];
  DEC
  if (ct >= 32) return;
  const unsigned short* A = (ct < 16) ? bfb + O_HZ : bfb + O_CZB;
  const float* Wf = (ct < 16) ? Wg_h : Wg_c;
  int jb = 64 * (ct & 15) + 16 * cg + lm;
  f32x4 acc = {};
  acc = mmKf<16>(A + (size_t)(R0 + lm) * HID + kh * 512 + lq8,
                 Wf + (size_t)jb * (2 * HID) + HID + kh * 512 + lq8, acc);
  dumpw(gat, acc, kh, cg, lane);
  __syncthreads();
  int prow = tid >> 5, cp2 = 2 * (tid & 31);
  int j0 = 64 * (ct & 15) + cp2;
  const float* bg = (ct < 16) ? bg_h : bg_c;
  float* G = (ct < 16) ? f32b + OF_GHZ : f32b + OF_GCZ;
  float2 vv;
  vv.x = gs(gat, prow, cp2) + bg[j0];
  vv.y = gs(gat, prow, cp2 + 1) + bg[j0 + 1];
  *(float2*)(G + (size_t)(R0 + prow) * HID + j0) = vv;
}

// ---- P1: gates0 = x@W_ih0^T + h0f@W_hh0^T -> h0n, c0n ----
__global__ __launch_bounds__(NTHR)
void k_p1(const float* __restrict__ bih, const float* __restrict__ bhh,
          unsigned char* __restrict__ ws) {
  __shared__ float gat[2048];
  DEC
  const int wrow = (lm >> 2) * HID + U0 + 4 * cg + (lm & 3);
  f32x4 acc = {};
  const unsigned short* aH = bfb + O_H0F + (size_t)(R0 + lm) * HID + lq8;
  const unsigned short* wH = bfb + O_WHH0 + (size_t)wrow * HID + lq8;
  if (kh == 0) {
    acc = mmK<8>(bfb + O_XB + (size_t)(R0 + lm) * INP + lq8,
                 bfb + O_WIH0 + (size_t)wrow * INP + lq8, acc);
    acc = mmK<12>(aH, wH, acc);
  } else {
    acc = mmK<20>(aH + 384, wH + 384, acc);
  }
  dumpw(gat, acc, kh, cg, lane);
  __syncthreads();
  if (tid < 256) {
    int pr = tid >> 4, pu = tid & 15, pc = pu >> 2, pd = pu & 3;
    int u = U0 + pu;
    float si = gs(gat, pr, 16*pc + pd),     sf = gs(gat, pr, 16*pc + 4 + pd);
    float sg = gs(gat, pr, 16*pc + 8 + pd), so = gs(gat, pr, 16*pc + 12 + pd);
    float gi_ = sigm(si + bih[u] + bhh[u]);
    float gf_ = sigm(sf + bih[HID+u] + bhh[HID+u]);
    float gg_ = ftanh(sg + bih[2*HID+u] + bhh[2*HID+u]);
    float go_ = sigm(so + bih[3*HID+u] + bhh[3*HID+u]);
    size_t gix = (size_t)(R0 + pr) * HID + u;
    float cn = gf_ * (f32b + OF_C0F)[gix] + gi_ * gg_;
    (bfb + O_H0N)[gix] = f2bf(go_ * ftanh(cn));
    (f32b + OF_C0N)[gix] = cn;
    (bfb + O_C0NB)[gix] = f2bf(cn);
  }
}

// ---- P2: gates1 = h0n@W_ih1^T + h1f@W_hh1^T -> h1n, c1n ----
__global__ __launch_bounds__(NTHR)
void k_p2(const float* __restrict__ bih, const float* __restrict__ bhh,
          unsigned char* __restrict__ ws) {
  __shared__ float gat[2048];
  DEC
  const int wrow = (lm >> 2) * HID + U0 + 4 * cg + (lm & 3);
  f32x4 acc = {};
  if (kh == 0)
    acc = mmK<32>(bfb + O_H0N + (size_t)(R0 + lm) * HID + lq8,
                  bfb + O_WIH1 + (size_t)wrow * HID + lq8, acc);
  else
    acc = mmK<32>(bfb + O_H1F + (size_t)(R0 + lm) * HID + lq8,
                  bfb + O_WHH1 + (size_t)wrow * HID + lq8, acc);
  dumpw(gat, acc, kh, cg, lane);
  __syncthreads();
  if (tid < 256) {
    int pr = tid >> 4, pu = tid & 15, pc = pu >> 2, pd = pu & 3;
    int u = U0 + pu;
    float si = gs(gat, pr, 16*pc + pd),     sf = gs(gat, pr, 16*pc + 4 + pd);
    float sg = gs(gat, pr, 16*pc + 8 + pd), so = gs(gat, pr, 16*pc + 12 + pd);
    float gi_ = sigm(si + bih[u] + bhh[u]);
    float gf_ = sigm(sf + bih[HID+u] + bhh[HID+u]);
    float gg_ = ftanh(sg + bih[2*HID+u] + bhh[2*HID+u]);
    float go_ = sigm(so + bih[3*HID+u] + bhh[3*HID+u]);
    size_t gix = (size_t)(R0 + pr) * HID + u;
    float cn = gf_ * (f32b + OF_C1F)[gix] + gi_ * gg_;
    (bfb + O_H1N)[gix] = f2bf(go_ * ftanh(cn));
    (f32b + OF_C1N)[gix] = cn;
    (bfb + O_C1NB)[gix] = f2bf(cn);
  }
}

// ---- P3: fc1(H1n)->Rb | gh0: H0n->H0f | gc0: C0n->C0f ----
__global__ __launch_bounds__(NTHR)
void k_p3(const float* __restrict__ bfc1, unsigned char* __restrict__ ws) {
  __shared__ float gat[2048];
  DEC
  const int role = (ct < 16) ? 0 : (ct < 32) ? 1 : (ct < 48) ? 2 : 3;
  if (role == 3) return;
  const int c03 = 64 * (ct & 15);
  const unsigned short* A = (role == 0) ? bfb + O_H1N : (role == 1) ? bfb + O_H0N : bfb + O_C0NB;
  const unsigned short* W = (role == 0) ? bfb + O_WFC1 : (role == 1) ? bfb + O_WGH : bfb + O_WGC;
  int j3 = c03 + 16 * cg + lm;
  f32x4 acc = {};
  acc = mmK<16>(A + (size_t)(R0 + lm) * HID + kh * 512 + lq8,
                W + (size_t)j3 * HID + kh * 512 + lq8, acc);
  dumpw(gat, acc, kh, cg, lane);
  __syncthreads();
  int prow = tid >> 5, cp2 = 2 * (tid & 31);
  float s0 = gs(gat, prow, cp2), s1 = gs(gat, prow, cp2 + 1);
  size_t gi0 = (size_t)(R0 + prow) * HID + c03 + cp2;
  if (role == 0) {
    float v0 = s0 + bfc1[c03 + cp2], v1 = s1 + bfc1[c03 + cp2 + 1];
    *(unsigned*)(bfb + O_RB + gi0) = packbf(v0 > 0.f ? v0 : 0.f, v1 > 0.f ? v1 : 0.f);
  } else if (role == 1) {
    unsigned hp = *(const unsigned*)(bfb + O_H0N + gi0);
    unsigned hz = *(const unsigned*)(bfb + O_HZ + gi0);
    float g0 = sigm(s0 + (f32b + OF_GHZ)[gi0]), g1 = sigm(s1 + (f32b + OF_GHZ)[gi0 + 1]);
    float n0 = g0 * bf2f((unsigned short)hp) + (1.f - g0) * bf2f((unsigned short)hz);
    float n1 = g0 == g0 ? g1 * bf2f((unsigned short)(hp >> 16)) + (1.f - g1) * bf2f((unsigned short)(hz >> 16)) : 0.f;
    *(unsigned*)(bfb + O_H0F + gi0) = packbf(n0, n1);
  } else {
    float2 cc = *(const float2*)(f32b + OF_C0N + gi0);
    float g0 = sigm(s0 + (f32b + OF_GCZ)[gi0]), g1 = sigm(s1 + (f32b + OF_GCZ)[gi0 + 1]);
    float2 r;
    r.x = g0 * cc.x + (1.f - g0) * (f32b + OF_CZ)[gi0];
    r.y = g1 * cc.y + (1.f - g1) * (f32b + OF_CZ)[gi0 + 1];
    *(float2*)(f32b + OF_C0F + gi0) = r;
  }
}

// ---- P4: fc2(Rb)->y,x | gh1: H1n->H1f | gc1: C1n->C1f ----
__global__ __launch_bounds__(NTHR)
void k_p4(const float* __restrict__ bfc2, float* __restrict__ out, int t, int T,
          unsigned char* __restrict__ ws) {
  __shared__ float gat[2048];
  DEC
  const bool isfc2 = (ct >= 48 && ct < 52);
  const int role = (ct < 16) ? 9 : (ct < 32) ? 1 : (ct < 48) ? 2 : 9;
  if (!isfc2 && role == 9) return;
  const int c03 = 64 * (ct & 15), c04 = 64 * (ct - 48);
  const unsigned short* A = isfc2 ? bfb + O_RB : (role == 1) ? bfb + O_H1N : bfb + O_C1NB;
  const unsigned short* W = isfc2 ? bfb + O_WFC2 : (role == 1) ? bfb + O_WGH : bfb + O_WGC;
  int j4 = (isfc2 ? c04 : c03) + 16 * cg + lm;
  f32x4 acc = {};
  acc = mmK<16>(A + (size_t)(R0 + lm) * HID + kh * 512 + lq8,
                W + (size_t)j4 * HID + kh * 512 + lq8, acc);
  dumpw(gat, acc, kh, cg, lane);
  __syncthreads();
  int prow = tid >> 5, cp2 = 2 * (tid & 31);
  float s0 = gs(gat, prow, cp2), s1 = gs(gat, prow, cp2 + 1);
  if (isfc2) {
    float v0 = s0 + bfc2[c04 + cp2], v1 = s1 + bfc2[c04 + cp2 + 1];
    size_t oix = ((size_t)(R0 + prow) * T + t) * OUTD + c04 + cp2;
    float2 vv; vv.x = v0; vv.y = v1;
    *(float2*)(out + oix) = vv;
    *(unsigned*)(bfb + O_XB + (size_t)(R0 + prow) * INP + c04 + cp2) = packbf(v0, v1);
  } else if (role == 1) {
    size_t gi0 = (size_t)(R0 + prow) * HID + c03 + cp2;
    unsigned hp = *(const unsigned*)(bfb + O_H1N + gi0);
    unsigned hz = *(const unsigned*)(bfb + O_HZ + gi0);
    float g0 = sigm(s0 + (f32b + OF_GHZ)[gi0]), g1 = sigm(s1 + (f32b + OF_GHZ)[gi0 + 1]);
    float n0 = g0 * bf2f((unsigned short)hp) + (1.f - g0) * bf2f((unsigned short)hz);
    float n1 = g1 * bf2f((unsigned short)(hp >> 16)) + (1.f - g1) * bf2f((unsigned short)(hz >> 16));
    *(unsigned*)(bfb + O_H1F + gi0) = packbf(n0, n1);
  } else {
    size_t gi0 = (size_t)(R0 + prow) * HID + c03 + cp2;
    float2 cc = *(const float2*)(f32b + OF_C1N + gi0);
    float g0 = sigm(s0 + (f32b + OF_GCZ)[gi0]), g1 = sigm(s1 + (f32b + OF_GCZ)[gi0 + 1]);
    float2 r;
    r.x = g0 * cc.x + (1.f - g0) * (f32b + OF_CZ)[gi0];
    r.y = g1 * cc.y + (1.f - g1) * (f32b + OF_CZ)[gi0 + 1];
    *(float2*)(f32b + OF_C1F + gi0) = r;
  }
}

extern "C" void kernel_launch(void* const* d_in, const int* in_sizes, int n_in,
                              void* d_out, int out_size, void* d_ws, size_t ws_size,
                              hipStream_t stream) {
  unsigned char* ws = (unsigned char*)d_ws;
  const float* z     = (const float*)d_in[0];
  const float* stok  = (const float*)d_in[2];
  const float* W_ih0 = (const float*)d_in[3];
  const float* W_hh0 = (const float*)d_in[4];
  const float* b_ih0 = (const float*)d_in[5];
  const float* b_hh0 = (const float*)d_in[6];
  const float* W_ih1 = (const float*)d_in[7];
  const float* W_hh1 = (const float*)d_in[8];
  const float* b_ih1 = (const float*)d_in[9];
  const float* b_hh1 = (const float*)d_in[10];
  const float* W_lh  = (const float*)d_in[11];
  const float* b_lh  = (const float*)d_in[12];
  const float* W_lc  = (const float*)d_in[13];
  const float* b_lc  = (const float*)d_in[14];
  const float* W_fc1 = (const float*)d_in[15];
  const float* b_fc1 = (const float*)d_in[16];
  const float* W_fc2 = (const float*)d_in[17];
  const float* b_fc2 = (const float*)d_in[18];
  const float* Wg_h  = (const float*)d_in[19];
  const float* bg_h  = (const float*)d_in[20];
  const float* Wg_c  = (const float*)d_in[21];
  const float* bg_c  = (const float*)d_in[22];

  const int T = out_size / (BSZ * OUTD);   // seq_length (device scalar not host-readable in capture)

  k_conv<<<dim3(2048), dim3(256), 0, stream>>>(z, stok, W_ih0, W_hh0, W_ih1, W_hh1,
                                               W_fc1, W_fc2, Wg_h, Wg_c, ws);
  k_phb<<<dim3(512), dim3(NTHR), 0, stream>>>(W_lh, b_lh, W_lc, b_lc, ws);
  k_phc<<<dim3(512), dim3(NTHR), 0, stream>>>(Wg_h, bg_h, Wg_c, bg_c, ws);

  for (int t = 0; t < T; ++t) {
    k_p1<<<dim3(512), dim3(NTHR), 0, stream>>>(b_ih0, b_hh0, ws);
    k_p2<<<dim3(512), dim3(NTHR), 0, stream>>>(b_ih1, b_hh1, ws);
    k_p3<<<dim3(512), dim3(NTHR), 0, stream>>>(b_fc1, ws);
    k_p4<<<dim3(512), dim3(NTHR), 0, stream>>>(b_fc2, (float*)d_out, t, T, ws);
  }
}